// Round 5
// baseline (123.843 us; speedup 1.0000x reference)
//
#include <hip/hip_runtime.h>

#define HW 28
#define NPIX 784   // 28*28
#define NIMG 64
#define MAXREC 5632  // 783*7 = 5481 worst case, padded to 22*256 for int4 batches
#define NOFF 3025    // 55*55 offsets
#define NOFFP 3072   // padded to 256*12
#define ND2 1459     // d2 <= 2*27^2 = 1458

// packed dx/dy (+1, 2 bits each) for {-1,0},{1,0},{0,-1},{0,1},
// {-1,-1},{-1,1},{1,-1},{1,1}; first 4 = 4-connectivity
#define DXPK 41048u
#define DYPK 34949u

// ---------------------------------------------------------------------------
// COMPILE-TIME offset table sorted by (d2, lin=dx*28+dy).
// Within-d2 order by lin equals order by j = i + lin for every pixel i ->
// identical to numpy stable argsort. (d2,lin) is a total order: a tie needs
// 2dx = 56dy + 785 (even = odd), impossible. Content verified on-HW in r3
// (absmax=0). Baked into the code object — no memcpy node (r3 lesson:
// pageable H2D graph node costs ~+10 us serial).
// Pack: d2<<16 | (dx+27)<<8 | (dy+27). Sentinel 0xFFFFFFFF -> out of bounds.
// ---------------------------------------------------------------------------
struct alignas(16) OffTbl { unsigned int t[NOFFP]; };

static constexpr OffTbl make_offtbl() {
    OffTbl o{};
    int cnt[ND2] = {};
    for (int dx = -27; dx <= 27; ++dx)
        for (int dy = -27; dy <= 27; ++dy)
            cnt[dx * dx + dy * dy]++;
    int pos[ND2] = {};
    int run = 0;
    for (int b = 0; b < ND2; ++b) { pos[b] = run; run += cnt[b]; }
    int lin_[NOFF] = {}, dxs[NOFF] = {}, dys[NOFF] = {};
    int p2[ND2] = {};
    for (int b = 0; b < ND2; ++b) p2[b] = pos[b];
    for (int dx = -27; dx <= 27; ++dx)
        for (int dy = -27; dy <= 27; ++dy) {
            int d2 = dx * dx + dy * dy;
            int s = p2[d2]++;
            lin_[s] = dx * HW + dy; dxs[s] = dx; dys[s] = dy;
        }
    for (int b = 0; b < ND2; ++b) {          // within-bin stable by lin
        int s0 = pos[b], s1 = pos[b] + cnt[b];
        for (int a = s0 + 1; a < s1; ++a) {
            int L = lin_[a], X = dxs[a], Y = dys[a];
            int c = a;
            while (c > s0 && lin_[c - 1] > L) {
                lin_[c] = lin_[c - 1]; dxs[c] = dxs[c - 1]; dys[c] = dys[c - 1];
                --c;
            }
            lin_[c] = L; dxs[c] = X; dys[c] = Y;
        }
    }
    for (int s = 0; s < NOFF; ++s)
        o.t[s] = ((unsigned)(dxs[s] * dxs[s] + dys[s] * dys[s]) << 16) |
                 ((unsigned)(dxs[s] + 27) << 8) | (unsigned)(dys[s] + 27);
    for (int s = NOFF; s < NOFFP; ++s) o.t[s] = 0xFFFFFFFFu;
    return o;
}

__device__ const OffTbl OTBC = make_offtbl();

// ---------------------------------------------------------------------------
// Kernel 1a: per-image sums + x transpose (64 blocks x 256 threads).
// ---------------------------------------------------------------------------
__global__ void xt_sums_kernel(const float* __restrict__ x,
                               float* __restrict__ sums,
                               float* __restrict__ xT) {
    int tid = threadIdx.x;
    int m = blockIdx.x;
    const float* xr = x + m * NPIX;
    float acc = 0.f;
    for (int j = tid; j < NPIX; j += 256) {
        float v = xr[j];
        xT[j * NIMG + m] = v;
        acc += v;
    }
    for (int off = 32; off > 0; off >>= 1) acc += __shfl_down(acc, off, 64);
    __shared__ float red[4];
    int lane = tid & 63, w = tid >> 6;
    if (lane == 0) red[w] = acc;
    __syncthreads();
    if (tid == 0) sums[m] = red[0] + red[1] + red[2] + red[3];
}

// ---------------------------------------------------------------------------
// Kernel 1b: per-pixel sorted row via ORDER-PRESERVING COMPACTION of the
// compile-time offset table, then DTM scan by wave 0 (lane = image) from
// LDS broadcast, x16 unroll (entries past the break point contribute exactly
// 0.0f -> bitwise-identical accumulation).
// ---------------------------------------------------------------------------
__global__ void __launch_bounds__(256) sortdtm_kernel(const float* __restrict__ xT,
                                                      const float* __restrict__ sums,
                                                      float* __restrict__ F) {
    __shared__ unsigned int tpl[NPIX];
    __shared__ int wtot[4];
    int tid = threadIdx.x;
    int i = blockIdx.x;
    int ii = i / HW, ij = i % HW;

    // ---- phase 1: compaction. 12 table entries per thread (3 x uint4). ----
    const uint4* o4 = (const uint4*)OTBC.t + tid * 3;
    uint4 qa = o4[0], qb = o4[1], qc = o4[2];
    unsigned int ent[12] = {qa.x, qa.y, qa.z, qa.w,
                            qb.x, qb.y, qb.z, qb.w,
                            qc.x, qc.y, qc.z, qc.w};
    int ct = 0;
    #pragma unroll
    for (int e = 0; e < 12; ++e) {
        int dx = (int)((ent[e] >> 8) & 255u) - 27;
        int dy = (int)(ent[e] & 255u) - 27;
        ct += ((unsigned)(ii + dx) < (unsigned)HW && (unsigned)(ij + dy) < (unsigned)HW) ? 1 : 0;
    }
    int lane = tid & 63, wv = tid >> 6;
    int p = ct;
    for (int off = 1; off < 64; off <<= 1) {
        int t2 = __shfl_up(p, off, 64);
        if (lane >= off) p += t2;
    }
    if (lane == 63) wtot[wv] = p;
    __syncthreads();
    int slot = p - ct;
    for (int w2 = 0; w2 < wv; ++w2) slot += wtot[w2];
    #pragma unroll
    for (int e = 0; e < 12; ++e) {
        int dx = (int)((ent[e] >> 8) & 255u) - 27;
        int dy = (int)(ent[e] & 255u) - 27;
        int ui = ii + dx, uj = ij + dy;
        if ((unsigned)ui < (unsigned)HW && (unsigned)uj < (unsigned)HW) {
            tpl[slot] = (unsigned)(ui * HW + uj) | (ent[e] & 0xFFFF0000u);
            ++slot;
        }
    }
    __syncthreads();

    // ---- phase 2: DTM scan, wave 0 only, lane = image, x16 unroll ----
    if (tid < 64) {
        float s = sums[tid];
        float bound1 = 0.05f * s, bound2 = 0.2f * s;
        float cum = 0.f, acc1 = 0.f, acc2 = 0.f;
        for (int t0 = 0; t0 < NPIX; t0 += 16) {   // 784 % 16 == 0
            unsigned int e[16];
            #pragma unroll
            for (int u = 0; u < 16; ++u) e[u] = tpl[t0 + u];   // LDS broadcast
            float w[16];
            #pragma unroll
            for (int u = 0; u < 16; ++u) w[u] = xT[(e[u] & 0xffffu) * NIMG + tid];
            #pragma unroll
            for (int u = 0; u < 16; ++u) {
                float d2 = (float)(e[u] >> 16);
                float ce = cum;
                cum += w[u];
                acc1 += fminf(fmaxf(bound1 - ce, 0.f), w[u]) * d2;
                acc2 += fminf(fmaxf(bound2 - ce, 0.f), w[u]) * d2;
            }
            if (__ballot(cum < bound2) == 0ull) break;  // all lanes done
        }
        F[0 * NIMG * NPIX + tid * NPIX + i] = sqrtf(acc1 / bound1);
        F[1 * NIMG * NPIX + tid * NPIX + i] = sqrtf(acc2 / bound2);
    }
}

// ---------------------------------------------------------------------------
// Kernel 3: fused RANK + UF (basin decomposition) + LANDSCAPE.
// 1024 threads (4 waves/SIMD). Round-1 lesson: latency-bound; the 16-wave-
// redundant rank's broadcast reads are cheap and its wave parallelism hides
// the dependent-load latency — do NOT consolidate onto fewer waves.
// Round-5 change: P5 batches widened 64 -> 256 records (4/lane, int4),
// cutting barrier+flatten rounds ~4x; merge order bitwise-identical
// ((lane,q) lex = global record order; static-unrolled selection chain,
// no dynamic register indexing). Landscape: 32-subset parallel top-3
// (selection-only -> float-exact).
// ---------------------------------------------------------------------------
template<int NN>   // NN = 4 (dir 0) or 8 (dir 1)
__device__ int uf_basin_run(const int* posA, const int* ordA,
                            int* bas, unsigned int* pb, int* comp,
                            int* recs, int* pairsI,
                            int2* mergeLDS, int* shInts, int* wtot16) {
    const int tid = threadIdx.x;
    const int lane = tid & 63, wv = tid >> 6;   // wv in [0,16)

    // ---- P2: steepest-descent forest ----
    for (int s = tid; s < NPIX; s += 1024) {
        int si = s / HW, sj = s % HW;
        int bestPos = posA[s], best = s;
        #pragma unroll
        for (int o = 0; o < NN; ++o) {
            int dx = ((DXPK >> (2 * o)) & 3) - 1;
            int dy = ((DYPK >> (2 * o)) & 3) - 1;
            int ui = si + dx, uj = sj + dy;
            if ((unsigned)ui < (unsigned)HW && (unsigned)uj < (unsigned)HW) {
                int u = ui * HW + uj;
                int pu = posA[u];
                if (pu < bestPos) { bestPos = pu; best = u; }
            }
        }
        bas[s] = best;
    }
    __syncthreads();

    // ---- P3: pointer jumping with convergence early-exit ----
    for (int it = 0; it < 10; ++it) {
        int changed = 0;
        for (int s = tid; s < NPIX; s += 1024) {
            int b = bas[s];
            int bb = bas[b];
            if (bb != b) { bas[s] = bb; changed = 1; }
        }
        if (__syncthreads_count(changed) == 0) break;
    }

    // ---- pack (pos<<10 | bas) for single-gather P4 ----
    for (int s = tid; s < NPIX; s += 1024)
        pb[s] = ((unsigned)posA[s] << 10) | (unsigned)bas[s];
    __syncthreads();

    // ---- P4: candidate records in rank order (single pass, r = tid) ----
    int nrec = 0;
    {
        int r = tid;
        int cnt = 0;
        int myr[NN - 1];
        int got[NN - 1];
        #pragma unroll
        for (int t = 0; t < NN - 1; ++t) { got[t] = -1; myr[t] = 0; }
        if (r > 0 && r < NPIX) {
            int v = ordA[r];
            int vi = v / HW, vj = v % HW;
            int pivot = (int)(pb[v] & 1023u);
            #pragma unroll
            for (int o = 0; o < NN; ++o) {
                int dx = ((DXPK >> (2 * o)) & 3) - 1;
                int dy = ((DYPK >> (2 * o)) & 3) - 1;
                int ui = vi + dx, uj = vj + dy;
                if ((unsigned)ui < (unsigned)HW && (unsigned)uj < (unsigned)HW) {
                    int u = ui * HW + uj;
                    unsigned e = pb[u];
                    if ((int)(e >> 10) < r) {
                        int b = (int)(e & 1023u);
                        bool dup = (b == pivot);
                        #pragma unroll
                        for (int t = 0; t < NN - 1; ++t) dup = dup || (got[t] == b);
                        if (!dup) {
                            #pragma unroll
                            for (int t = 0; t < NN - 1; ++t)
                                if (t == cnt) { got[t] = b; myr[t] = (v << 20) | (pivot << 10) | b; }
                            cnt++;
                        }
                    }
                }
            }
        }
        // block-wide exclusive prefix of cnt (16 wave partials)
        int p = cnt;
        for (int off = 1; off < 64; off <<= 1) {
            int t2 = __shfl_up(p, off, 64);
            if (lane >= off) p += t2;
        }
        if (lane == 63) wtot16[wv] = p;
        __syncthreads();
        int wadd = 0;
        for (int w2 = 0; w2 < wv; ++w2) wadd += wtot16[w2];
        int tot = 0;
        #pragma unroll
        for (int w2 = 0; w2 < 16; ++w2) tot += wtot16[w2];
        int excl = wadd + p - cnt;
        #pragma unroll
        for (int t = 0; t < NN - 1; ++t)
            if (t < cnt) recs[excl + t] = myr[t];
        nrec = tot;
        __syncthreads();
    }

    // ---- P5: ballot-driven serial UF (wave 0), 256 recs/batch (4/lane) ----
    // Record index = base + lane*4 + q, so (lane,q) lex order == global rank
    // order; ffs picks lowest lane, its lowest unresolved q == globally
    // lowest unresolved record -> merge sequence identical to 64-wide P5.
    int k = 0;
    for (int base = 0; base < nrec; base += 256) {
        int nrem = 0;
        if (wv == 0) {
            int idx0 = base + lane * 4;
            int4 rl = *(const int4*)&recs[idx0];   // 16B-aligned; padded array
            int rec4[4] = {rl.x, rl.y, rl.z, rl.w};
            int ka[4], kb[4];
            #pragma unroll
            for (int q = 0; q < 4; ++q) {
                if (idx0 + q >= nrec) rec4[q] = 0;   // resolves to comp[0]==comp[0]
                int pa = (rec4[q] >> 10) & 1023, pbn = rec4[q] & 1023;
                ka[q] = comp[pa]; kb[q] = comp[pbn];
            }
            for (;;) {
                // static-unrolled select of lowest unresolved q (no dyn idx)
                int selKa = ka[3], selKb = kb[3], selRec = rec4[3];
                bool has = (ka[3] != kb[3]);
                #pragma unroll
                for (int q = 2; q >= 0; --q) {
                    bool u = (ka[q] != kb[q]);
                    selKa  = u ? ka[q]  : selKa;
                    selKb  = u ? kb[q]  : selKb;
                    selRec = u ? rec4[q] : selRec;
                    has = has || u;
                }
                unsigned long long d = __ballot(has);
                if (d == 0ull) break;
                int i = (int)__ffsll((long long)d) - 1;  // lowest lane = lowest rank
                int sA = __builtin_amdgcn_readlane(selKa, i);
                int sB = __builtin_amdgcn_readlane(selKb, i);
                int w = min(sA, sB), l = max(sA, sB);    // uniform scalars
                int sv = __builtin_amdgcn_readlane(selRec, i) >> 20;
                if (lane == 0) {
                    pairsI[k] = (l & 1023) | (sv << 10);
                    mergeLDS[nrem] = make_int2(l, w);
                }
                k++;
                #pragma unroll
                for (int q = 0; q < 4; ++q) {
                    ka[q] = (ka[q] == l) ? w : ka[q];
                    kb[q] = (kb[q] == l) ? w : kb[q];
                }
                nrem++;
                if (nrem == 63) {              // overflow guard (rare): wave-0 flatten
                    for (int s = lane; s < NPIX; s += 64) {
                        int cv = comp[s], c0 = cv;
                        for (int e = 0; e < nrem; ++e) {
                            int2 me = mergeLDS[e];
                            cv = (cv == me.x) ? me.y : cv;
                        }
                        if (cv != c0) comp[s] = cv;
                    }
                    #pragma unroll
                    for (int q = 0; q < 4; ++q) {
                        int pa = (rec4[q] >> 10) & 1023, pbn = rec4[q] & 1023;
                        ka[q] = comp[pa]; kb[q] = comp[pbn];
                    }
                    nrem = 0;
                }
            }
            if (lane == 0) shInts[0] = nrem;
        }
        __syncthreads();
        int nr = shInts[0];
        if (nr > 0) {                          // flatten with all 1024 threads
            for (int s = tid; s < NPIX; s += 1024) {
                int cv = comp[s], c0 = cv;
                for (int e = 0; e < nr; ++e) {
                    int2 me = mergeLDS[e];
                    cv = (cv == me.x) ? me.y : cv;
                }
                if (cv != c0) comp[s] = cv;
            }
        }
        __syncthreads();
    }
    if (tid == 0) shInts[1] = k;
    __syncthreads();
    return shInts[1];
}

__global__ void __launch_bounds__(1024) uf_land_kernel(const float* __restrict__ F,
                                                       float* __restrict__ LAM1,
                                                       float* __restrict__ LAM2) {
    __shared__ int posA[NPIX], ordA[NPIX], bas[NPIX], comp[NPIX], pairsI[NPIX];
    __shared__ unsigned int pbArr[NPIX];  // packed (pos,bas) for P4
    __shared__ alignas(16) unsigned long long key64[NPIX];  // rank keys
    __shared__ float fv[NPIX];
    __shared__ alignas(16) int recs[MAXREC];  // P5 records; reused as landscape partials
    __shared__ int2 mergeLDS[64];
    __shared__ int shInts[2];
    __shared__ int wtot16[16];
    int tid = threadIdx.x;
    int task = blockIdx.x;
    int feat = task >> 7;
    int dir = (task >> 6) & 1;
    int m = task & 63;
    const float* fr = F + feat * NIMG * NPIX + m * NPIX;

    // load values + precomputed packed u64 sort keys (values >= 0: bits
    // monotone; dir==1 uses ~bits so both dirs are the same ascending cmp)
    for (int j = tid; j < NPIX; j += 1024) {
        float f = fr[j];
        fv[j] = f;
        unsigned int b = __float_as_uint(f);
        if (dir) b = ~b;
        key64[j] = ((unsigned long long)b << 10) | (unsigned)j;
    }
    __syncthreads();

    // ---- fused rank: b128 reads of prepacked u64 keys, 1 cmp each ----
    if (tid < NPIX) {
        unsigned long long pki = key64[tid];
        int rank = 0;
        const ulonglong2* k2 = (const ulonglong2*)key64;
        for (int c = 0; c < NPIX / 2; ++c) {
            ulonglong2 kv = k2[c];
            rank += (int)(kv.x < pki) + (int)(kv.y < pki);
        }
        posA[tid] = rank;
        ordA[rank] = tid;
    }
    __syncthreads();
    for (int s = tid; s < NPIX; s += 1024) comp[s] = (posA[s] << 10) | s;
    // (comp init needs no barrier before P2: P2 reads only posA)

    int k;
    if (dir == 0) k = uf_basin_run<4>(posA, ordA, bas, pbArr, comp, recs, pairsI,
                                      mergeLDS, shInts, wtot16);
    else          k = uf_basin_run<8>(posA, ordA, bas, pbArr, comp, recs, pairsI,
                                      mergeLDS, shInts, wtot16);

    // ---- parallel landscape: 32 pair-subsets x 32 t-values, then merge ----
    // top3(union) == top3(top3 of each subset); selection only -> float-exact.
    float start = (feat == 0) ? 0.f : 1.f;
    float end   = (feat == 0) ? 7.f : 8.f;
    {
        int sub = tid >> 5;          // 0..31
        int t = tid & 31;
        float tv = start + (end - start) * ((float)t / 31.f);
        float v0 = 0.f, v1 = 0.f, v2 = 0.f;
        for (int p = sub; p < k; p += 32) {
            int pi = pairsI[p];
            float fb = fv[pi & 1023], fd = fv[pi >> 10];
            float bb = dir ? fd : fb;
            float dd = dir ? fb : fd;
            float tent = fmaxf(fminf(tv - bb, dd - tv), 0.f);
            if (tent > v0)      { v2 = v1; v1 = v0; v0 = tent; }
            else if (tent > v1) { v2 = v1; v1 = tent; }
            else if (tent > v2) { v2 = tent; }
        }
        float* part = (float*)recs;               // recs dead after P5
        int bse = (sub * 32 + t) * 3;
        part[bse] = v0; part[bse + 1] = v1; part[bse + 2] = v2;
    }
    __syncthreads();
    if (tid < 32) {
        int t = tid;
        const float* part = (const float*)recs;
        float v0 = 0.f, v1 = 0.f, v2 = 0.f;
        for (int s2 = 0; s2 < 32; ++s2) {
            int bse = (s2 * 32 + t) * 3;
            #pragma unroll
            for (int q = 0; q < 3; ++q) {
                float x = part[bse + q];
                if (x > v0)      { v2 = v1; v1 = v0; v0 = x; }
                else if (x > v1) { v2 = v1; v1 = x; }
                else if (x > v2) { v2 = x; }
            }
        }
        if (feat == 0) {
            float* lam = LAM1 + m * 128 + dir * 64;
            lam[0 * 32 + t] = v0;
            lam[1 * 32 + t] = v1;
        } else {
            float* lam = LAM2 + m * 192 + dir * 96;
            lam[0 * 32 + t] = v0;
            lam[1 * 32 + t] = v1;
            lam[2 * 32 + t] = v2;
        }
    }
}

// ---------------------------------------------------------------------------
// Kernel 4: MLP head. One block (64 threads) per image.
// ---------------------------------------------------------------------------
__global__ void mlp_kernel(const float* __restrict__ LAM1, const float* __restrict__ LAM2,
                           const float* __restrict__ w1, const float* __restrict__ b1,
                           const float* __restrict__ w2, const float* __restrict__ b2,
                           const float* __restrict__ wf, const float* __restrict__ bf,
                           float* __restrict__ out) {
    __shared__ float xc[64];
    int m = blockIdx.x;
    int n = threadIdx.x;
    if (n < 32) {
        float acc = b1[n];
        const float* l = LAM1 + m * 128;
        for (int c = 0; c < 128; ++c) acc += w1[n * 128 + c] * l[c];
        xc[n] = fmaxf(acc, 0.f);
    } else {
        int n2 = n - 32;
        float acc = b2[n2];
        const float* l = LAM2 + m * 192;
        for (int c = 0; c < 192; ++c) acc += w2[n2 * 192 + c] * l[c];
        xc[n] = fmaxf(acc, 0.f);
    }
    __syncthreads();
    if (n < 10) {
        float acc = bf[n];
        for (int c = 0; c < 64; ++c) acc += wf[n * 64 + c] * xc[c];
        out[m * 10 + n] = acc;
    }
}

extern "C" void kernel_launch(void* const* d_in, const int* in_sizes, int n_in,
                              void* d_out, int out_size, void* d_ws, size_t ws_size,
                              hipStream_t stream) {
    const float* x  = (const float*)d_in[0];
    const float* w1 = (const float*)d_in[1];
    const float* b1 = (const float*)d_in[2];
    const float* w2 = (const float*)d_in[3];
    const float* b2 = (const float*)d_in[4];
    const float* wf = (const float*)d_in[5];
    const float* bf = (const float*)d_in[6];
    float* out = (float*)d_out;

    char* ws = (char*)d_ws;
    size_t off = 0;
    float* XT   = (float*)(ws + off); off += (size_t)NPIX * NIMG * 4;
    float* SUMS = (float*)(ws + off); off += 256;
    float* F    = (float*)(ws + off); off += (size_t)2 * NIMG * NPIX * 4;
    float* LAM1 = (float*)(ws + off); off += (size_t)NIMG * 128 * 4;
    float* LAM2 = (float*)(ws + off); off += (size_t)NIMG * 192 * 4;

    xt_sums_kernel<<<NIMG, 256, 0, stream>>>(x, SUMS, XT);
    sortdtm_kernel<<<NPIX, 256, 0, stream>>>(XT, SUMS, F);
    uf_land_kernel<<<256, 1024, 0, stream>>>(F, LAM1, LAM2);
    mlp_kernel<<<NIMG, 64, 0, stream>>>(LAM1, LAM2, w1, b1, w2, b2, wf, bf, out);
}

// Round 6
// 121.926 us; speedup vs baseline: 1.0157x; 1.0157x over previous
//
#include <hip/hip_runtime.h>

#define HW 28
#define NPIX 784   // 28*28
#define NIMG 64
#define MAXREC 5504  // 783 * 7 worst case
#define NOFF 3025    // 55*55 offsets
#define NOFFP 3072   // padded to 256*12
#define ND2 1459     // d2 <= 2*27^2 = 1458

// packed dx/dy (+1, 2 bits each) for {-1,0},{1,0},{0,-1},{0,1},
// {-1,-1},{-1,1},{1,-1},{1,1}; first 4 = 4-connectivity
#define DXPK 41048u
#define DYPK 34949u

// ---------------------------------------------------------------------------
// COMPILE-TIME offset table sorted by (d2, lin=dx*28+dy).
// Within-d2 order by lin equals order by j = i + lin for every pixel i ->
// identical to numpy stable argsort. (d2,lin) is a total order: a tie needs
// 2dx = 56dy + 785 (even = odd), impossible. Content verified on-HW in r3
// (absmax=0). Baked into the code object — no memcpy node (r3 lesson:
// pageable H2D graph node costs ~+10 us serial).
// Pack: d2<<16 | (dx+27)<<8 | (dy+27). Sentinel 0xFFFFFFFF -> out of bounds.
// ---------------------------------------------------------------------------
struct alignas(16) OffTbl { unsigned int t[NOFFP]; };

static constexpr OffTbl make_offtbl() {
    OffTbl o{};
    int cnt[ND2] = {};
    for (int dx = -27; dx <= 27; ++dx)
        for (int dy = -27; dy <= 27; ++dy)
            cnt[dx * dx + dy * dy]++;
    int pos[ND2] = {};
    int run = 0;
    for (int b = 0; b < ND2; ++b) { pos[b] = run; run += cnt[b]; }
    int lin_[NOFF] = {}, dxs[NOFF] = {}, dys[NOFF] = {};
    int p2[ND2] = {};
    for (int b = 0; b < ND2; ++b) p2[b] = pos[b];
    for (int dx = -27; dx <= 27; ++dx)
        for (int dy = -27; dy <= 27; ++dy) {
            int d2 = dx * dx + dy * dy;
            int s = p2[d2]++;
            lin_[s] = dx * HW + dy; dxs[s] = dx; dys[s] = dy;
        }
    for (int b = 0; b < ND2; ++b) {          // within-bin stable by lin
        int s0 = pos[b], s1 = pos[b] + cnt[b];
        for (int a = s0 + 1; a < s1; ++a) {
            int L = lin_[a], X = dxs[a], Y = dys[a];
            int c = a;
            while (c > s0 && lin_[c - 1] > L) {
                lin_[c] = lin_[c - 1]; dxs[c] = dxs[c - 1]; dys[c] = dys[c - 1];
                --c;
            }
            lin_[c] = L; dxs[c] = X; dys[c] = Y;
        }
    }
    for (int s = 0; s < NOFF; ++s)
        o.t[s] = ((unsigned)(dxs[s] * dxs[s] + dys[s] * dys[s]) << 16) |
                 ((unsigned)(dxs[s] + 27) << 8) | (unsigned)(dys[s] + 27);
    for (int s = NOFF; s < NOFFP; ++s) o.t[s] = 0xFFFFFFFFu;
    return o;
}

__device__ const OffTbl OTBC = make_offtbl();

// ---------------------------------------------------------------------------
// Kernel 1a: per-image sums + x transpose (64 blocks x 256 threads).
// ---------------------------------------------------------------------------
__global__ void xt_sums_kernel(const float* __restrict__ x,
                               float* __restrict__ sums,
                               float* __restrict__ xT) {
    int tid = threadIdx.x;
    int m = blockIdx.x;
    const float* xr = x + m * NPIX;
    float acc = 0.f;
    for (int j = tid; j < NPIX; j += 256) {
        float v = xr[j];
        xT[j * NIMG + m] = v;
        acc += v;
    }
    for (int off = 32; off > 0; off >>= 1) acc += __shfl_down(acc, off, 64);
    __shared__ float red[4];
    int lane = tid & 63, w = tid >> 6;
    if (lane == 0) red[w] = acc;
    __syncthreads();
    if (tid == 0) sums[m] = red[0] + red[1] + red[2] + red[3];
}

// ---------------------------------------------------------------------------
// Kernel 1b: per-pixel sorted row via ORDER-PRESERVING COMPACTION of the
// compile-time offset table, then DTM scan by wave 0 (lane = image) from
// LDS broadcast, x16 unroll (entries past the break point contribute exactly
// 0.0f -> bitwise-identical accumulation).
// ---------------------------------------------------------------------------
__global__ void __launch_bounds__(256) sortdtm_kernel(const float* __restrict__ xT,
                                                      const float* __restrict__ sums,
                                                      float* __restrict__ F) {
    __shared__ unsigned int tpl[NPIX];
    __shared__ int wtot[4];
    int tid = threadIdx.x;
    int i = blockIdx.x;
    int ii = i / HW, ij = i % HW;

    // ---- phase 1: compaction. 12 table entries per thread (3 x uint4). ----
    const uint4* o4 = (const uint4*)OTBC.t + tid * 3;
    uint4 qa = o4[0], qb = o4[1], qc = o4[2];
    unsigned int ent[12] = {qa.x, qa.y, qa.z, qa.w,
                            qb.x, qb.y, qb.z, qb.w,
                            qc.x, qc.y, qc.z, qc.w};
    int ct = 0;
    #pragma unroll
    for (int e = 0; e < 12; ++e) {
        int dx = (int)((ent[e] >> 8) & 255u) - 27;
        int dy = (int)(ent[e] & 255u) - 27;
        ct += ((unsigned)(ii + dx) < (unsigned)HW && (unsigned)(ij + dy) < (unsigned)HW) ? 1 : 0;
    }
    int lane = tid & 63, wv = tid >> 6;
    int p = ct;
    for (int off = 1; off < 64; off <<= 1) {
        int t2 = __shfl_up(p, off, 64);
        if (lane >= off) p += t2;
    }
    if (lane == 63) wtot[wv] = p;
    __syncthreads();
    int slot = p - ct;
    for (int w2 = 0; w2 < wv; ++w2) slot += wtot[w2];
    #pragma unroll
    for (int e = 0; e < 12; ++e) {
        int dx = (int)((ent[e] >> 8) & 255u) - 27;
        int dy = (int)(ent[e] & 255u) - 27;
        int ui = ii + dx, uj = ij + dy;
        if ((unsigned)ui < (unsigned)HW && (unsigned)uj < (unsigned)HW) {
            tpl[slot] = (unsigned)(ui * HW + uj) | (ent[e] & 0xFFFF0000u);
            ++slot;
        }
    }
    __syncthreads();

    // ---- phase 2: DTM scan, wave 0 only, lane = image, x16 unroll ----
    if (tid < 64) {
        float s = sums[tid];
        float bound1 = 0.05f * s, bound2 = 0.2f * s;
        float cum = 0.f, acc1 = 0.f, acc2 = 0.f;
        for (int t0 = 0; t0 < NPIX; t0 += 16) {   // 784 % 16 == 0
            unsigned int e[16];
            #pragma unroll
            for (int u = 0; u < 16; ++u) e[u] = tpl[t0 + u];   // LDS broadcast
            float w[16];
            #pragma unroll
            for (int u = 0; u < 16; ++u) w[u] = xT[(e[u] & 0xffffu) * NIMG + tid];
            #pragma unroll
            for (int u = 0; u < 16; ++u) {
                float d2 = (float)(e[u] >> 16);
                float ce = cum;
                cum += w[u];
                acc1 += fminf(fmaxf(bound1 - ce, 0.f), w[u]) * d2;
                acc2 += fminf(fmaxf(bound2 - ce, 0.f), w[u]) * d2;
            }
            if (__ballot(cum < bound2) == 0ull) break;  // all lanes done
        }
        F[0 * NIMG * NPIX + tid * NPIX + i] = sqrtf(acc1 / bound1);
        F[1 * NIMG * NPIX + tid * NPIX + i] = sqrtf(acc2 / bound2);
    }
}

// ---------------------------------------------------------------------------
// Kernel 3: fused RANK + UF (basin decomposition) + LANDSCAPE.
// 1024 threads (4 waves/SIMD). Round-1 lesson: latency-bound; the 16-wave-
// redundant rank's broadcast reads are cheap and its wave parallelism hides
// the dependent-load latency — do NOT consolidate onto fewer waves.
// Round-5 lesson: P5 wide batches regress — the per-merge selection chain
// runs on the serial critical path every merge (~+4 us/block); keep the
// 64-wide P5 (round-4 form). This round's single change: 32-subset parallel
// landscape (selection-only -> float-exact).
// ---------------------------------------------------------------------------
template<int NN>   // NN = 4 (dir 0) or 8 (dir 1)
__device__ int uf_basin_run(const int* posA, const int* ordA,
                            int* bas, unsigned int* pb, int* comp,
                            int* recs, int* pairsI,
                            int2* mergeLDS, int* shInts, int* wtot16) {
    const int tid = threadIdx.x;
    const int lane = tid & 63, wv = tid >> 6;   // wv in [0,16)

    // ---- P2: steepest-descent forest ----
    for (int s = tid; s < NPIX; s += 1024) {
        int si = s / HW, sj = s % HW;
        int bestPos = posA[s], best = s;
        #pragma unroll
        for (int o = 0; o < NN; ++o) {
            int dx = ((DXPK >> (2 * o)) & 3) - 1;
            int dy = ((DYPK >> (2 * o)) & 3) - 1;
            int ui = si + dx, uj = sj + dy;
            if ((unsigned)ui < (unsigned)HW && (unsigned)uj < (unsigned)HW) {
                int u = ui * HW + uj;
                int pu = posA[u];
                if (pu < bestPos) { bestPos = pu; best = u; }
            }
        }
        bas[s] = best;
    }
    __syncthreads();

    // ---- P3: pointer jumping with convergence early-exit ----
    for (int it = 0; it < 10; ++it) {
        int changed = 0;
        for (int s = tid; s < NPIX; s += 1024) {
            int b = bas[s];
            int bb = bas[b];
            if (bb != b) { bas[s] = bb; changed = 1; }
        }
        if (__syncthreads_count(changed) == 0) break;
    }

    // ---- pack (pos<<10 | bas) for single-gather P4 ----
    for (int s = tid; s < NPIX; s += 1024)
        pb[s] = ((unsigned)posA[s] << 10) | (unsigned)bas[s];
    __syncthreads();

    // ---- P4: candidate records in rank order (single pass, r = tid) ----
    int nrec = 0;
    {
        int r = tid;
        int cnt = 0;
        int myr[NN - 1];
        int got[NN - 1];
        #pragma unroll
        for (int t = 0; t < NN - 1; ++t) { got[t] = -1; myr[t] = 0; }
        if (r > 0 && r < NPIX) {
            int v = ordA[r];
            int vi = v / HW, vj = v % HW;
            int pivot = (int)(pb[v] & 1023u);
            #pragma unroll
            for (int o = 0; o < NN; ++o) {
                int dx = ((DXPK >> (2 * o)) & 3) - 1;
                int dy = ((DYPK >> (2 * o)) & 3) - 1;
                int ui = vi + dx, uj = vj + dy;
                if ((unsigned)ui < (unsigned)HW && (unsigned)uj < (unsigned)HW) {
                    int u = ui * HW + uj;
                    unsigned e = pb[u];
                    if ((int)(e >> 10) < r) {
                        int b = (int)(e & 1023u);
                        bool dup = (b == pivot);
                        #pragma unroll
                        for (int t = 0; t < NN - 1; ++t) dup = dup || (got[t] == b);
                        if (!dup) {
                            #pragma unroll
                            for (int t = 0; t < NN - 1; ++t)
                                if (t == cnt) { got[t] = b; myr[t] = (v << 20) | (pivot << 10) | b; }
                            cnt++;
                        }
                    }
                }
            }
        }
        // block-wide exclusive prefix of cnt (16 wave partials)
        int p = cnt;
        for (int off = 1; off < 64; off <<= 1) {
            int t2 = __shfl_up(p, off, 64);
            if (lane >= off) p += t2;
        }
        if (lane == 63) wtot16[wv] = p;
        __syncthreads();
        int wadd = 0;
        for (int w2 = 0; w2 < wv; ++w2) wadd += wtot16[w2];
        int tot = 0;
        #pragma unroll
        for (int w2 = 0; w2 < 16; ++w2) tot += wtot16[w2];
        int excl = wadd + p - cnt;
        #pragma unroll
        for (int t = 0; t < NN - 1; ++t)
            if (t < cnt) recs[excl + t] = myr[t];
        nrec = tot;
        __syncthreads();
    }

    // ---- P5: ballot-driven serial UF (wave 0), block-wide flatten ----
    int k = 0;
    for (int base = 0; base < nrec; base += 64) {
        int nrem = 0;
        if (wv == 0) {
            int idx = base + lane;
            int rec = (idx < nrec) ? recs[idx] : 0;
            int pa = (rec >> 10) & 1023, pbn = rec & 1023;
            int ka = 0, kb = 0;
            if (idx < nrec) { ka = comp[pa]; kb = comp[pbn]; }
            for (;;) {
                unsigned long long d = __ballot(ka != kb);
                if (d == 0ull) break;
                int i = (int)__ffsll((long long)d) - 1;   // lowest lane = lowest rank
                int sA = __builtin_amdgcn_readlane(ka, i);
                int sB = __builtin_amdgcn_readlane(kb, i);
                int w = min(sA, sB), l = max(sA, sB);     // uniform scalars
                int sv = __builtin_amdgcn_readlane(rec, i) >> 20;
                if (lane == 0) {
                    pairsI[k] = (l & 1023) | (sv << 10);
                    mergeLDS[nrem] = make_int2(l, w);
                }
                k++;
                ka = (ka == l) ? w : ka;
                kb = (kb == l) ? w : kb;
                nrem++;
                if (nrem == 63) {              // overflow guard (rare): wave-0 flatten
                    for (int s = lane; s < NPIX; s += 64) {
                        int cv = comp[s], c0 = cv;
                        for (int e = 0; e < nrem; ++e) {
                            int2 me = mergeLDS[e];
                            cv = (cv == me.x) ? me.y : cv;
                        }
                        if (cv != c0) comp[s] = cv;
                    }
                    if (idx < nrec) { ka = comp[pa]; kb = comp[pbn]; }
                    nrem = 0;
                }
            }
            if (lane == 0) shInts[0] = nrem;
        }
        __syncthreads();
        int nr = shInts[0];
        if (nr > 0) {                          // flatten with all 1024 threads
            for (int s = tid; s < NPIX; s += 1024) {
                int cv = comp[s], c0 = cv;
                for (int e = 0; e < nr; ++e) {
                    int2 me = mergeLDS[e];
                    cv = (cv == me.x) ? me.y : cv;
                }
                if (cv != c0) comp[s] = cv;
            }
        }
        __syncthreads();
    }
    if (tid == 0) shInts[1] = k;
    __syncthreads();
    return shInts[1];
}

__global__ void __launch_bounds__(1024) uf_land_kernel(const float* __restrict__ F,
                                                       float* __restrict__ LAM1,
                                                       float* __restrict__ LAM2) {
    __shared__ int posA[NPIX], ordA[NPIX], bas[NPIX], comp[NPIX], pairsI[NPIX];
    __shared__ unsigned int pbArr[NPIX];  // packed (pos,bas) for P4
    __shared__ alignas(16) unsigned long long key64[NPIX];  // rank keys
    __shared__ float fv[NPIX];
    __shared__ int recs[MAXREC];  // P5 records; reused as landscape partials
    __shared__ int2 mergeLDS[64];
    __shared__ int shInts[2];
    __shared__ int wtot16[16];
    int tid = threadIdx.x;
    int task = blockIdx.x;
    int feat = task >> 7;
    int dir = (task >> 6) & 1;
    int m = task & 63;
    const float* fr = F + feat * NIMG * NPIX + m * NPIX;

    // load values + precomputed packed u64 sort keys (values >= 0: bits
    // monotone; dir==1 uses ~bits so both dirs are the same ascending cmp)
    for (int j = tid; j < NPIX; j += 1024) {
        float f = fr[j];
        fv[j] = f;
        unsigned int b = __float_as_uint(f);
        if (dir) b = ~b;
        key64[j] = ((unsigned long long)b << 10) | (unsigned)j;
    }
    __syncthreads();

    // ---- fused rank: b128 reads of prepacked u64 keys, 1 cmp each ----
    if (tid < NPIX) {
        unsigned long long pki = key64[tid];
        int rank = 0;
        const ulonglong2* k2 = (const ulonglong2*)key64;
        for (int c = 0; c < NPIX / 2; ++c) {
            ulonglong2 kv = k2[c];
            rank += (int)(kv.x < pki) + (int)(kv.y < pki);
        }
        posA[tid] = rank;
        ordA[rank] = tid;
    }
    __syncthreads();
    for (int s = tid; s < NPIX; s += 1024) comp[s] = (posA[s] << 10) | s;
    // (comp init needs no barrier before P2: P2 reads only posA)

    int k;
    if (dir == 0) k = uf_basin_run<4>(posA, ordA, bas, pbArr, comp, recs, pairsI,
                                      mergeLDS, shInts, wtot16);
    else          k = uf_basin_run<8>(posA, ordA, bas, pbArr, comp, recs, pairsI,
                                      mergeLDS, shInts, wtot16);

    // ---- parallel landscape: 32 pair-subsets x 32 t-values, then merge ----
    // top3(union) == top3(top3 of each subset); selection only -> float-exact.
    float start = (feat == 0) ? 0.f : 1.f;
    float end   = (feat == 0) ? 7.f : 8.f;
    {
        int sub = tid >> 5;          // 0..31
        int t = tid & 31;
        float tv = start + (end - start) * ((float)t / 31.f);
        float v0 = 0.f, v1 = 0.f, v2 = 0.f;
        for (int p = sub; p < k; p += 32) {
            int pi = pairsI[p];
            float fb = fv[pi & 1023], fd = fv[pi >> 10];
            float bb = dir ? fd : fb;
            float dd = dir ? fb : fd;
            float tent = fmaxf(fminf(tv - bb, dd - tv), 0.f);
            if (tent > v0)      { v2 = v1; v1 = v0; v0 = tent; }
            else if (tent > v1) { v2 = v1; v1 = tent; }
            else if (tent > v2) { v2 = tent; }
        }
        float* part = (float*)recs;               // recs dead after P5
        int bse = (sub * 32 + t) * 3;
        part[bse] = v0; part[bse + 1] = v1; part[bse + 2] = v2;
    }
    __syncthreads();
    if (tid < 32) {
        int t = tid;
        const float* part = (const float*)recs;
        float v0 = 0.f, v1 = 0.f, v2 = 0.f;
        for (int s2 = 0; s2 < 32; ++s2) {
            int bse = (s2 * 32 + t) * 3;
            #pragma unroll
            for (int q = 0; q < 3; ++q) {
                float x = part[bse + q];
                if (x > v0)      { v2 = v1; v1 = v0; v0 = x; }
                else if (x > v1) { v2 = v1; v1 = x; }
                else if (x > v2) { v2 = x; }
            }
        }
        if (feat == 0) {
            float* lam = LAM1 + m * 128 + dir * 64;
            lam[0 * 32 + t] = v0;
            lam[1 * 32 + t] = v1;
        } else {
            float* lam = LAM2 + m * 192 + dir * 96;
            lam[0 * 32 + t] = v0;
            lam[1 * 32 + t] = v1;
            lam[2 * 32 + t] = v2;
        }
    }
}

// ---------------------------------------------------------------------------
// Kernel 4: MLP head. One block (64 threads) per image.
// ---------------------------------------------------------------------------
__global__ void mlp_kernel(const float* __restrict__ LAM1, const float* __restrict__ LAM2,
                           const float* __restrict__ w1, const float* __restrict__ b1,
                           const float* __restrict__ w2, const float* __restrict__ b2,
                           const float* __restrict__ wf, const float* __restrict__ bf,
                           float* __restrict__ out) {
    __shared__ float xc[64];
    int m = blockIdx.x;
    int n = threadIdx.x;
    if (n < 32) {
        float acc = b1[n];
        const float* l = LAM1 + m * 128;
        for (int c = 0; c < 128; ++c) acc += w1[n * 128 + c] * l[c];
        xc[n] = fmaxf(acc, 0.f);
    } else {
        int n2 = n - 32;
        float acc = b2[n2];
        const float* l = LAM2 + m * 192;
        for (int c = 0; c < 192; ++c) acc += w2[n2 * 192 + c] * l[c];
        xc[n] = fmaxf(acc, 0.f);
    }
    __syncthreads();
    if (n < 10) {
        float acc = bf[n];
        for (int c = 0; c < 64; ++c) acc += wf[n * 64 + c] * xc[c];
        out[m * 10 + n] = acc;
    }
}

extern "C" void kernel_launch(void* const* d_in, const int* in_sizes, int n_in,
                              void* d_out, int out_size, void* d_ws, size_t ws_size,
                              hipStream_t stream) {
    const float* x  = (const float*)d_in[0];
    const float* w1 = (const float*)d_in[1];
    const float* b1 = (const float*)d_in[2];
    const float* w2 = (const float*)d_in[3];
    const float* b2 = (const float*)d_in[4];
    const float* wf = (const float*)d_in[5];
    const float* bf = (const float*)d_in[6];
    float* out = (float*)d_out;

    char* ws = (char*)d_ws;
    size_t off = 0;
    float* XT   = (float*)(ws + off); off += (size_t)NPIX * NIMG * 4;
    float* SUMS = (float*)(ws + off); off += 256;
    float* F    = (float*)(ws + off); off += (size_t)2 * NIMG * NPIX * 4;
    float* LAM1 = (float*)(ws + off); off += (size_t)NIMG * 128 * 4;
    float* LAM2 = (float*)(ws + off); off += (size_t)NIMG * 192 * 4;

    xt_sums_kernel<<<NIMG, 256, 0, stream>>>(x, SUMS, XT);
    sortdtm_kernel<<<NPIX, 256, 0, stream>>>(XT, SUMS, F);
    uf_land_kernel<<<256, 1024, 0, stream>>>(F, LAM1, LAM2);
    mlp_kernel<<<NIMG, 64, 0, stream>>>(LAM1, LAM2, w1, b1, w2, b2, wf, bf, out);
}

// Round 7
// 120.664 us; speedup vs baseline: 1.0263x; 1.0105x over previous
//
#include <hip/hip_runtime.h>

#define HW 28
#define NPIX 784   // 28*28
#define NIMG 64
#define MAXREC 5504  // 783 * 7 worst case
#define NOFF 3025    // 55*55 offsets
#define NOFFP 3072   // padded to 256*12
#define ND2 1459     // d2 <= 2*27^2 = 1458

// packed dx/dy (+1, 2 bits each) for {-1,0},{1,0},{0,-1},{0,1},
// {-1,-1},{-1,1},{1,-1},{1,1}; first 4 = 4-connectivity
#define DXPK 41048u
#define DYPK 34949u

// ---------------------------------------------------------------------------
// COMPILE-TIME offset table sorted by (d2, lin=dx*28+dy).
// Within-d2 order by lin equals order by j = i + lin for every pixel i ->
// identical to numpy stable argsort. (d2,lin) is a total order: a tie needs
// 2dx = 56dy + 785 (even = odd), impossible. Content verified on-HW in r3
// (absmax=0). Baked into the code object — no memcpy node (r3 lesson:
// pageable H2D graph node costs ~+10 us serial).
// Pack: d2<<16 | (dx+27)<<8 | (dy+27). Sentinel 0xFFFFFFFF -> out of bounds.
// ---------------------------------------------------------------------------
struct alignas(16) OffTbl { unsigned int t[NOFFP]; };

static constexpr OffTbl make_offtbl() {
    OffTbl o{};
    int cnt[ND2] = {};
    for (int dx = -27; dx <= 27; ++dx)
        for (int dy = -27; dy <= 27; ++dy)
            cnt[dx * dx + dy * dy]++;
    int pos[ND2] = {};
    int run = 0;
    for (int b = 0; b < ND2; ++b) { pos[b] = run; run += cnt[b]; }
    int lin_[NOFF] = {}, dxs[NOFF] = {}, dys[NOFF] = {};
    int p2[ND2] = {};
    for (int b = 0; b < ND2; ++b) p2[b] = pos[b];
    for (int dx = -27; dx <= 27; ++dx)
        for (int dy = -27; dy <= 27; ++dy) {
            int d2 = dx * dx + dy * dy;
            int s = p2[d2]++;
            lin_[s] = dx * HW + dy; dxs[s] = dx; dys[s] = dy;
        }
    for (int b = 0; b < ND2; ++b) {          // within-bin stable by lin
        int s0 = pos[b], s1 = pos[b] + cnt[b];
        for (int a = s0 + 1; a < s1; ++a) {
            int L = lin_[a], X = dxs[a], Y = dys[a];
            int c = a;
            while (c > s0 && lin_[c - 1] > L) {
                lin_[c] = lin_[c - 1]; dxs[c] = dxs[c - 1]; dys[c] = dys[c - 1];
                --c;
            }
            lin_[c] = L; dxs[c] = X; dys[c] = Y;
        }
    }
    for (int s = 0; s < NOFF; ++s)
        o.t[s] = ((unsigned)(dxs[s] * dxs[s] + dys[s] * dys[s]) << 16) |
                 ((unsigned)(dxs[s] + 27) << 8) | (unsigned)(dys[s] + 27);
    for (int s = NOFF; s < NOFFP; ++s) o.t[s] = 0xFFFFFFFFu;
    return o;
}

__device__ const OffTbl OTBC = make_offtbl();

// ---------------------------------------------------------------------------
// Kernel 1a: per-image sums + x transpose (64 blocks x 256 threads).
// ---------------------------------------------------------------------------
__global__ void xt_sums_kernel(const float* __restrict__ x,
                               float* __restrict__ sums,
                               float* __restrict__ xT) {
    int tid = threadIdx.x;
    int m = blockIdx.x;
    const float* xr = x + m * NPIX;
    float acc = 0.f;
    for (int j = tid; j < NPIX; j += 256) {
        float v = xr[j];
        xT[j * NIMG + m] = v;
        acc += v;
    }
    for (int off = 32; off > 0; off >>= 1) acc += __shfl_down(acc, off, 64);
    __shared__ float red[4];
    int lane = tid & 63, w = tid >> 6;
    if (lane == 0) red[w] = acc;
    __syncthreads();
    if (tid == 0) sums[m] = red[0] + red[1] + red[2] + red[3];
}

// ---------------------------------------------------------------------------
// Kernel 1b: per-pixel sorted row via ORDER-PRESERVING COMPACTION of the
// compile-time offset table, then DTM scan by wave 0 (lane = image) from
// LDS broadcast, x16 unroll (entries past the break point contribute exactly
// 0.0f -> bitwise-identical accumulation).
// ---------------------------------------------------------------------------
__global__ void __launch_bounds__(256) sortdtm_kernel(const float* __restrict__ xT,
                                                      const float* __restrict__ sums,
                                                      float* __restrict__ F) {
    __shared__ unsigned int tpl[NPIX];
    __shared__ int wtot[4];
    int tid = threadIdx.x;
    int i = blockIdx.x;
    int ii = i / HW, ij = i % HW;

    // ---- phase 1: compaction. 12 table entries per thread (3 x uint4). ----
    const uint4* o4 = (const uint4*)OTBC.t + tid * 3;
    uint4 qa = o4[0], qb = o4[1], qc = o4[2];
    unsigned int ent[12] = {qa.x, qa.y, qa.z, qa.w,
                            qb.x, qb.y, qb.z, qb.w,
                            qc.x, qc.y, qc.z, qc.w};
    int ct = 0;
    #pragma unroll
    for (int e = 0; e < 12; ++e) {
        int dx = (int)((ent[e] >> 8) & 255u) - 27;
        int dy = (int)(ent[e] & 255u) - 27;
        ct += ((unsigned)(ii + dx) < (unsigned)HW && (unsigned)(ij + dy) < (unsigned)HW) ? 1 : 0;
    }
    int lane = tid & 63, wv = tid >> 6;
    int p = ct;
    for (int off = 1; off < 64; off <<= 1) {
        int t2 = __shfl_up(p, off, 64);
        if (lane >= off) p += t2;
    }
    if (lane == 63) wtot[wv] = p;
    __syncthreads();
    int slot = p - ct;
    for (int w2 = 0; w2 < wv; ++w2) slot += wtot[w2];
    #pragma unroll
    for (int e = 0; e < 12; ++e) {
        int dx = (int)((ent[e] >> 8) & 255u) - 27;
        int dy = (int)(ent[e] & 255u) - 27;
        int ui = ii + dx, uj = ij + dy;
        if ((unsigned)ui < (unsigned)HW && (unsigned)uj < (unsigned)HW) {
            tpl[slot] = (unsigned)(ui * HW + uj) | (ent[e] & 0xFFFF0000u);
            ++slot;
        }
    }
    __syncthreads();

    // ---- phase 2: DTM scan, wave 0 only, lane = image, x16 unroll ----
    if (tid < 64) {
        float s = sums[tid];
        float bound1 = 0.05f * s, bound2 = 0.2f * s;
        float cum = 0.f, acc1 = 0.f, acc2 = 0.f;
        for (int t0 = 0; t0 < NPIX; t0 += 16) {   // 784 % 16 == 0
            unsigned int e[16];
            #pragma unroll
            for (int u = 0; u < 16; ++u) e[u] = tpl[t0 + u];   // LDS broadcast
            float w[16];
            #pragma unroll
            for (int u = 0; u < 16; ++u) w[u] = xT[(e[u] & 0xffffu) * NIMG + tid];
            #pragma unroll
            for (int u = 0; u < 16; ++u) {
                float d2 = (float)(e[u] >> 16);
                float ce = cum;
                cum += w[u];
                acc1 += fminf(fmaxf(bound1 - ce, 0.f), w[u]) * d2;
                acc2 += fminf(fmaxf(bound2 - ce, 0.f), w[u]) * d2;
            }
            if (__ballot(cum < bound2) == 0ull) break;  // all lanes done
        }
        F[0 * NIMG * NPIX + tid * NPIX + i] = sqrtf(acc1 / bound1);
        F[1 * NIMG * NPIX + tid * NPIX + i] = sqrtf(acc2 / bound2);
    }
}

// ---------------------------------------------------------------------------
// Kernel 3: fused RANK + UF (basin decomposition) + LANDSCAPE.
// 1024 threads (4 waves/SIMD). Ledger of measured lessons:
//  r1: rank must stay 16-wave redundant (broadcast LDS reads are cheap;
//      wave parallelism hides dependent-load latency).
//  r5: P5 wide batches regress (+4/block): per-merge select chain sits on
//      the serial critical path.
//  r6: parallel landscape regresses (+3): merge pass + barrier cost ~= the
//      serial k-loop it replaces; keep landscape serial on 32 lanes.
//  r7 (this round): P5 with NO per-batch barriers/flatten — cumulative
//      merge list replayed per batch (the old overflow-guard pattern, made
//      the main path). comp[] is dead after P5, so the global flatten was
//      pure bookkeeping. Merge sequence bitwise-identical.
// ---------------------------------------------------------------------------
template<int NN>   // NN = 4 (dir 0) or 8 (dir 1)
__device__ int uf_basin_run(const int* posA, const int* ordA,
                            int* bas, unsigned int* pb, int* comp,
                            int* recs, int* pairsI,
                            int2* mergeLDS, int* shInts, int* wtot16) {
    const int tid = threadIdx.x;
    const int lane = tid & 63, wv = tid >> 6;   // wv in [0,16)

    // ---- P2: steepest-descent forest ----
    for (int s = tid; s < NPIX; s += 1024) {
        int si = s / HW, sj = s % HW;
        int bestPos = posA[s], best = s;
        #pragma unroll
        for (int o = 0; o < NN; ++o) {
            int dx = ((DXPK >> (2 * o)) & 3) - 1;
            int dy = ((DYPK >> (2 * o)) & 3) - 1;
            int ui = si + dx, uj = sj + dy;
            if ((unsigned)ui < (unsigned)HW && (unsigned)uj < (unsigned)HW) {
                int u = ui * HW + uj;
                int pu = posA[u];
                if (pu < bestPos) { bestPos = pu; best = u; }
            }
        }
        bas[s] = best;
    }
    __syncthreads();

    // ---- P3: pointer jumping with convergence early-exit ----
    for (int it = 0; it < 10; ++it) {
        int changed = 0;
        for (int s = tid; s < NPIX; s += 1024) {
            int b = bas[s];
            int bb = bas[b];
            if (bb != b) { bas[s] = bb; changed = 1; }
        }
        if (__syncthreads_count(changed) == 0) break;
    }

    // ---- pack (pos<<10 | bas) for single-gather P4 ----
    for (int s = tid; s < NPIX; s += 1024)
        pb[s] = ((unsigned)posA[s] << 10) | (unsigned)bas[s];
    __syncthreads();

    // ---- P4: candidate records in rank order (single pass, r = tid) ----
    int nrec = 0;
    {
        int r = tid;
        int cnt = 0;
        int myr[NN - 1];
        int got[NN - 1];
        #pragma unroll
        for (int t = 0; t < NN - 1; ++t) { got[t] = -1; myr[t] = 0; }
        if (r > 0 && r < NPIX) {
            int v = ordA[r];
            int vi = v / HW, vj = v % HW;
            int pivot = (int)(pb[v] & 1023u);
            #pragma unroll
            for (int o = 0; o < NN; ++o) {
                int dx = ((DXPK >> (2 * o)) & 3) - 1;
                int dy = ((DYPK >> (2 * o)) & 3) - 1;
                int ui = vi + dx, uj = vj + dy;
                if ((unsigned)ui < (unsigned)HW && (unsigned)uj < (unsigned)HW) {
                    int u = ui * HW + uj;
                    unsigned e = pb[u];
                    if ((int)(e >> 10) < r) {
                        int b = (int)(e & 1023u);
                        bool dup = (b == pivot);
                        #pragma unroll
                        for (int t = 0; t < NN - 1; ++t) dup = dup || (got[t] == b);
                        if (!dup) {
                            #pragma unroll
                            for (int t = 0; t < NN - 1; ++t)
                                if (t == cnt) { got[t] = b; myr[t] = (v << 20) | (pivot << 10) | b; }
                            cnt++;
                        }
                    }
                }
            }
        }
        // block-wide exclusive prefix of cnt (16 wave partials)
        int p = cnt;
        for (int off = 1; off < 64; off <<= 1) {
            int t2 = __shfl_up(p, off, 64);
            if (lane >= off) p += t2;
        }
        if (lane == 63) wtot16[wv] = p;
        __syncthreads();
        int wadd = 0;
        for (int w2 = 0; w2 < wv; ++w2) wadd += wtot16[w2];
        int tot = 0;
        #pragma unroll
        for (int w2 = 0; w2 < 16; ++w2) tot += wtot16[w2];
        int excl = wadd + p - cnt;
        #pragma unroll
        for (int t = 0; t < NN - 1; ++t)
            if (t < cnt) recs[excl + t] = myr[t];
        nrec = tot;
        __syncthreads();
    }

    // ---- P5: ballot-driven serial UF, ENTIRELY on wave 0, no barriers ----
    // comp[] is never read after P5, so the old per-batch 1024-thread
    // flatten (+2 barriers/batch) was pure bookkeeping. Instead keep the
    // cumulative merge list (l->w, in merge order) in mergeLDS and replay
    // it onto each new batch's freshly loaded labels (same cross-lane
    // LDS-within-wave pattern the old overflow guard used). Batch order and
    // ballot-ffs selection unchanged -> merge sequence bitwise-identical.
    int k = 0;
    if (wv == 0) {
        for (int base = 0; base < nrec; base += 64) {
            int idx = base + lane;
            int rec = (idx < nrec) ? recs[idx] : 0;   // rec 0 -> comp[0]==comp[0], inert
            int pa = (rec >> 10) & 1023, pbn = rec & 1023;
            int ka = comp[pa], kb = comp[pbn];
            for (int e = 0; e < k; ++e) {             // replay prior merges
                int2 me = mergeLDS[e];
                ka = (ka == me.x) ? me.y : ka;
                kb = (kb == me.x) ? me.y : kb;
            }
            for (;;) {
                unsigned long long d = __ballot(ka != kb);
                if (d == 0ull) break;
                int i = (int)__ffsll((long long)d) - 1;   // lowest lane = lowest rank
                int sA = __builtin_amdgcn_readlane(ka, i);
                int sB = __builtin_amdgcn_readlane(kb, i);
                int w = min(sA, sB), l = max(sA, sB);     // uniform scalars
                int sv = __builtin_amdgcn_readlane(rec, i) >> 20;
                if (lane == 0) {
                    pairsI[k] = (l & 1023) | (sv << 10);
                    mergeLDS[k] = make_int2(l, w);
                }
                k++;
                ka = (ka == l) ? w : ka;
                kb = (kb == l) ? w : kb;
            }
        }
        if (lane == 0) shInts[1] = k;
    }
    __syncthreads();
    return shInts[1];
}

__global__ void __launch_bounds__(1024) uf_land_kernel(const float* __restrict__ F,
                                                       float* __restrict__ LAM1,
                                                       float* __restrict__ LAM2) {
    __shared__ int posA[NPIX], ordA[NPIX], bas[NPIX], comp[NPIX], pairsI[NPIX];
    __shared__ unsigned int pbArr[NPIX];  // packed (pos,bas) for P4
    __shared__ alignas(16) unsigned long long key64[NPIX];  // rank keys
    __shared__ float fv[NPIX];
    __shared__ int recs[MAXREC];
    __shared__ int2 mergeLDS[NPIX];   // cumulative merge list (<= 783 merges)
    __shared__ int shInts[2];
    __shared__ int wtot16[16];
    int tid = threadIdx.x;
    int task = blockIdx.x;
    int feat = task >> 7;
    int dir = (task >> 6) & 1;
    int m = task & 63;
    const float* fr = F + feat * NIMG * NPIX + m * NPIX;

    // load values + precomputed packed u64 sort keys (values >= 0: bits
    // monotone; dir==1 uses ~bits so both dirs are the same ascending cmp)
    for (int j = tid; j < NPIX; j += 1024) {
        float f = fr[j];
        fv[j] = f;
        unsigned int b = __float_as_uint(f);
        if (dir) b = ~b;
        key64[j] = ((unsigned long long)b << 10) | (unsigned)j;
    }
    __syncthreads();

    // ---- fused rank: b128 reads of prepacked u64 keys, 1 cmp each ----
    if (tid < NPIX) {
        unsigned long long pki = key64[tid];
        int rank = 0;
        const ulonglong2* k2 = (const ulonglong2*)key64;
        for (int c = 0; c < NPIX / 2; ++c) {
            ulonglong2 kv = k2[c];
            rank += (int)(kv.x < pki) + (int)(kv.y < pki);
        }
        posA[tid] = rank;
        ordA[rank] = tid;
    }
    __syncthreads();
    for (int s = tid; s < NPIX; s += 1024) comp[s] = (posA[s] << 10) | s;
    // (comp init needs no barrier before P2: P2 reads only posA)

    int k;
    if (dir == 0) k = uf_basin_run<4>(posA, ordA, bas, pbArr, comp, recs, pairsI,
                                      mergeLDS, shInts, wtot16);
    else          k = uf_basin_run<8>(posA, ordA, bas, pbArr, comp, recs, pairsI,
                                      mergeLDS, shInts, wtot16);

    // ---- fused landscape: top-3 tents directly from pairsI (broadcast) ----
    if (tid < 32) {
        int t = tid;
        float start = (feat == 0) ? 0.f : 1.f;
        float end   = (feat == 0) ? 7.f : 8.f;
        float tv = start + (end - start) * ((float)t / 31.f);
        float v0 = 0.f, v1 = 0.f, v2 = 0.f;
        for (int p = 0; p < k; ++p) {
            int pi = pairsI[p];                   // same addr all lanes
            float fb = fv[pi & 1023], fd = fv[pi >> 10];
            float bb = dir ? fd : fb;
            float dd = dir ? fb : fd;
            float tent = fmaxf(fminf(tv - bb, dd - tv), 0.f);
            if (tent > v0)      { v2 = v1; v1 = v0; v0 = tent; }
            else if (tent > v1) { v2 = v1; v1 = tent; }
            else if (tent > v2) { v2 = tent; }
        }
        if (feat == 0) {
            float* lam = LAM1 + m * 128 + dir * 64;
            lam[0 * 32 + t] = v0;
            lam[1 * 32 + t] = v1;
        } else {
            float* lam = LAM2 + m * 192 + dir * 96;
            lam[0 * 32 + t] = v0;
            lam[1 * 32 + t] = v1;
            lam[2 * 32 + t] = v2;
        }
    }
}

// ---------------------------------------------------------------------------
// Kernel 4: MLP head. One block (64 threads) per image.
// ---------------------------------------------------------------------------
__global__ void mlp_kernel(const float* __restrict__ LAM1, const float* __restrict__ LAM2,
                           const float* __restrict__ w1, const float* __restrict__ b1,
                           const float* __restrict__ w2, const float* __restrict__ b2,
                           const float* __restrict__ wf, const float* __restrict__ bf,
                           float* __restrict__ out) {
    __shared__ float xc[64];
    int m = blockIdx.x;
    int n = threadIdx.x;
    if (n < 32) {
        float acc = b1[n];
        const float* l = LAM1 + m * 128;
        for (int c = 0; c < 128; ++c) acc += w1[n * 128 + c] * l[c];
        xc[n] = fmaxf(acc, 0.f);
    } else {
        int n2 = n - 32;
        float acc = b2[n2];
        const float* l = LAM2 + m * 192;
        for (int c = 0; c < 192; ++c) acc += w2[n2 * 192 + c] * l[c];
        xc[n] = fmaxf(acc, 0.f);
    }
    __syncthreads();
    if (n < 10) {
        float acc = bf[n];
        for (int c = 0; c < 64; ++c) acc += wf[n * 64 + c] * xc[c];
        out[m * 10 + n] = acc;
    }
}

extern "C" void kernel_launch(void* const* d_in, const int* in_sizes, int n_in,
                              void* d_out, int out_size, void* d_ws, size_t ws_size,
                              hipStream_t stream) {
    const float* x  = (const float*)d_in[0];
    const float* w1 = (const float*)d_in[1];
    const float* b1 = (const float*)d_in[2];
    const float* w2 = (const float*)d_in[3];
    const float* b2 = (const float*)d_in[4];
    const float* wf = (const float*)d_in[5];
    const float* bf = (const float*)d_in[6];
    float* out = (float*)d_out;

    char* ws = (char*)d_ws;
    size_t off = 0;
    float* XT   = (float*)(ws + off); off += (size_t)NPIX * NIMG * 4;
    float* SUMS = (float*)(ws + off); off += 256;
    float* F    = (float*)(ws + off); off += (size_t)2 * NIMG * NPIX * 4;
    float* LAM1 = (float*)(ws + off); off += (size_t)NIMG * 128 * 4;
    float* LAM2 = (float*)(ws + off); off += (size_t)NIMG * 192 * 4;

    xt_sums_kernel<<<NIMG, 256, 0, stream>>>(x, SUMS, XT);
    sortdtm_kernel<<<NPIX, 256, 0, stream>>>(XT, SUMS, F);
    uf_land_kernel<<<256, 1024, 0, stream>>>(F, LAM1, LAM2);
    mlp_kernel<<<NIMG, 64, 0, stream>>>(LAM1, LAM2, w1, b1, w2, b2, wf, bf, out);
}

// Round 8
// 118.571 us; speedup vs baseline: 1.0445x; 1.0177x over previous
//
#include <hip/hip_runtime.h>

#define HW 28
#define NPIX 784   // 28*28
#define NIMG 64
#define MAXREC 5504  // 783 * 7 worst case
#define NOFF 3025    // 55*55 offsets
#define NOFFP 3072   // padded to 256*12
#define ND2 1459     // d2 <= 2*27^2 = 1458

// packed dx/dy (+1, 2 bits each) for {-1,0},{1,0},{0,-1},{0,1},
// {-1,-1},{-1,1},{1,-1},{1,1}; first 4 = 4-connectivity
#define DXPK 41048u
#define DYPK 34949u

// ---------------------------------------------------------------------------
// COMPILE-TIME offset table sorted by (d2, lin=dx*28+dy).
// Within-d2 order by lin equals order by j = i + lin for every pixel i ->
// identical to numpy stable argsort. (d2,lin) is a total order: a tie needs
// 2dx = 56dy + 785 (even = odd), impossible. Content verified on-HW in r3
// (absmax=0). Baked into the code object — no memcpy node (r3 lesson:
// pageable H2D graph node costs ~+10 us serial).
// Pack: d2<<16 | (dx+27)<<8 | (dy+27). Sentinel 0xFFFFFFFF -> out of bounds.
// ---------------------------------------------------------------------------
struct alignas(16) OffTbl { unsigned int t[NOFFP]; };

static constexpr OffTbl make_offtbl() {
    OffTbl o{};
    int cnt[ND2] = {};
    for (int dx = -27; dx <= 27; ++dx)
        for (int dy = -27; dy <= 27; ++dy)
            cnt[dx * dx + dy * dy]++;
    int pos[ND2] = {};
    int run = 0;
    for (int b = 0; b < ND2; ++b) { pos[b] = run; run += cnt[b]; }
    int lin_[NOFF] = {}, dxs[NOFF] = {}, dys[NOFF] = {};
    int p2[ND2] = {};
    for (int b = 0; b < ND2; ++b) p2[b] = pos[b];
    for (int dx = -27; dx <= 27; ++dx)
        for (int dy = -27; dy <= 27; ++dy) {
            int d2 = dx * dx + dy * dy;
            int s = p2[d2]++;
            lin_[s] = dx * HW + dy; dxs[s] = dx; dys[s] = dy;
        }
    for (int b = 0; b < ND2; ++b) {          // within-bin stable by lin
        int s0 = pos[b], s1 = pos[b] + cnt[b];
        for (int a = s0 + 1; a < s1; ++a) {
            int L = lin_[a], X = dxs[a], Y = dys[a];
            int c = a;
            while (c > s0 && lin_[c - 1] > L) {
                lin_[c] = lin_[c - 1]; dxs[c] = dxs[c - 1]; dys[c] = dys[c - 1];
                --c;
            }
            lin_[c] = L; dxs[c] = X; dys[c] = Y;
        }
    }
    for (int s = 0; s < NOFF; ++s)
        o.t[s] = ((unsigned)(dxs[s] * dxs[s] + dys[s] * dys[s]) << 16) |
                 ((unsigned)(dxs[s] + 27) << 8) | (unsigned)(dys[s] + 27);
    for (int s = NOFF; s < NOFFP; ++s) o.t[s] = 0xFFFFFFFFu;
    return o;
}

__device__ const OffTbl OTBC = make_offtbl();

// ---------------------------------------------------------------------------
// Kernel 1a: per-image sums + x transpose (64 blocks x 256 threads).
// ---------------------------------------------------------------------------
__global__ void xt_sums_kernel(const float* __restrict__ x,
                               float* __restrict__ sums,
                               float* __restrict__ xT) {
    int tid = threadIdx.x;
    int m = blockIdx.x;
    const float* xr = x + m * NPIX;
    float acc = 0.f;
    for (int j = tid; j < NPIX; j += 256) {
        float v = xr[j];
        xT[j * NIMG + m] = v;
        acc += v;
    }
    for (int off = 32; off > 0; off >>= 1) acc += __shfl_down(acc, off, 64);
    __shared__ float red[4];
    int lane = tid & 63, w = tid >> 6;
    if (lane == 0) red[w] = acc;
    __syncthreads();
    if (tid == 0) sums[m] = red[0] + red[1] + red[2] + red[3];
}

// ---------------------------------------------------------------------------
// Kernel 1b: per-pixel sorted row via ORDER-PRESERVING COMPACTION of the
// compile-time offset table, then DTM scan by wave 0 (lane = image) from
// LDS broadcast, x16 unroll (entries past the break point contribute exactly
// 0.0f -> bitwise-identical accumulation).
// ---------------------------------------------------------------------------
__global__ void __launch_bounds__(256) sortdtm_kernel(const float* __restrict__ xT,
                                                      const float* __restrict__ sums,
                                                      float* __restrict__ F) {
    __shared__ unsigned int tpl[NPIX];
    __shared__ int wtot[4];
    int tid = threadIdx.x;
    int i = blockIdx.x;
    int ii = i / HW, ij = i % HW;

    // ---- phase 1: compaction. 12 table entries per thread (3 x uint4). ----
    const uint4* o4 = (const uint4*)OTBC.t + tid * 3;
    uint4 qa = o4[0], qb = o4[1], qc = o4[2];
    unsigned int ent[12] = {qa.x, qa.y, qa.z, qa.w,
                            qb.x, qb.y, qb.z, qb.w,
                            qc.x, qc.y, qc.z, qc.w};
    int ct = 0;
    #pragma unroll
    for (int e = 0; e < 12; ++e) {
        int dx = (int)((ent[e] >> 8) & 255u) - 27;
        int dy = (int)(ent[e] & 255u) - 27;
        ct += ((unsigned)(ii + dx) < (unsigned)HW && (unsigned)(ij + dy) < (unsigned)HW) ? 1 : 0;
    }
    int lane = tid & 63, wv = tid >> 6;
    int p = ct;
    for (int off = 1; off < 64; off <<= 1) {
        int t2 = __shfl_up(p, off, 64);
        if (lane >= off) p += t2;
    }
    if (lane == 63) wtot[wv] = p;
    __syncthreads();
    int slot = p - ct;
    for (int w2 = 0; w2 < wv; ++w2) slot += wtot[w2];
    #pragma unroll
    for (int e = 0; e < 12; ++e) {
        int dx = (int)((ent[e] >> 8) & 255u) - 27;
        int dy = (int)(ent[e] & 255u) - 27;
        int ui = ii + dx, uj = ij + dy;
        if ((unsigned)ui < (unsigned)HW && (unsigned)uj < (unsigned)HW) {
            tpl[slot] = (unsigned)(ui * HW + uj) | (ent[e] & 0xFFFF0000u);
            ++slot;
        }
    }
    __syncthreads();

    // ---- phase 2: DTM scan, wave 0 only, lane = image, x16 unroll ----
    if (tid < 64) {
        float s = sums[tid];
        float bound1 = 0.05f * s, bound2 = 0.2f * s;
        float cum = 0.f, acc1 = 0.f, acc2 = 0.f;
        for (int t0 = 0; t0 < NPIX; t0 += 16) {   // 784 % 16 == 0
            unsigned int e[16];
            #pragma unroll
            for (int u = 0; u < 16; ++u) e[u] = tpl[t0 + u];   // LDS broadcast
            float w[16];
            #pragma unroll
            for (int u = 0; u < 16; ++u) w[u] = xT[(e[u] & 0xffffu) * NIMG + tid];
            #pragma unroll
            for (int u = 0; u < 16; ++u) {
                float d2 = (float)(e[u] >> 16);
                float ce = cum;
                cum += w[u];
                acc1 += fminf(fmaxf(bound1 - ce, 0.f), w[u]) * d2;
                acc2 += fminf(fmaxf(bound2 - ce, 0.f), w[u]) * d2;
            }
            if (__ballot(cum < bound2) == 0ull) break;  // all lanes done
        }
        F[0 * NIMG * NPIX + tid * NPIX + i] = sqrtf(acc1 / bound1);
        F[1 * NIMG * NPIX + tid * NPIX + i] = sqrtf(acc2 / bound2);
    }
}

// ---------------------------------------------------------------------------
// Kernel 3: fused RANK + UF (basin decomposition) + LANDSCAPE.
// 1024 threads (4 waves/SIMD). Measured-best r4 structure. Ledger:
//  r1: rank must stay 16-wave redundant (broadcast LDS reads cheap; wave
//      parallelism hides dependent-load latency) — 196-thread rank +5.
//  r5: 256-wide P5 batches +5 (per-merge select chain on serial path).
//  r6: parallel landscape +3 (merge pass + barrier ~= serial k-loop).
//  r7: barrier-free P5 with cumulative replay +2 (replay iterations
//      ~batches*k/2 on serial path ate the barrier savings).
//  => 256 tasks / 256 CUs: wall = per-task serial path; this 64-wide
//     barriered P5 + serial landscape is the measured optimum.
// ---------------------------------------------------------------------------
template<int NN>   // NN = 4 (dir 0) or 8 (dir 1)
__device__ int uf_basin_run(const int* posA, const int* ordA,
                            int* bas, unsigned int* pb, int* comp,
                            int* recs, int* pairsI,
                            int2* mergeLDS, int* shInts, int* wtot16) {
    const int tid = threadIdx.x;
    const int lane = tid & 63, wv = tid >> 6;   // wv in [0,16)

    // ---- P2: steepest-descent forest ----
    for (int s = tid; s < NPIX; s += 1024) {
        int si = s / HW, sj = s % HW;
        int bestPos = posA[s], best = s;
        #pragma unroll
        for (int o = 0; o < NN; ++o) {
            int dx = ((DXPK >> (2 * o)) & 3) - 1;
            int dy = ((DYPK >> (2 * o)) & 3) - 1;
            int ui = si + dx, uj = sj + dy;
            if ((unsigned)ui < (unsigned)HW && (unsigned)uj < (unsigned)HW) {
                int u = ui * HW + uj;
                int pu = posA[u];
                if (pu < bestPos) { bestPos = pu; best = u; }
            }
        }
        bas[s] = best;
    }
    __syncthreads();

    // ---- P3: pointer jumping with convergence early-exit ----
    for (int it = 0; it < 10; ++it) {
        int changed = 0;
        for (int s = tid; s < NPIX; s += 1024) {
            int b = bas[s];
            int bb = bas[b];
            if (bb != b) { bas[s] = bb; changed = 1; }
        }
        if (__syncthreads_count(changed) == 0) break;
    }

    // ---- pack (pos<<10 | bas) for single-gather P4 ----
    for (int s = tid; s < NPIX; s += 1024)
        pb[s] = ((unsigned)posA[s] << 10) | (unsigned)bas[s];
    __syncthreads();

    // ---- P4: candidate records in rank order (single pass, r = tid) ----
    int nrec = 0;
    {
        int r = tid;
        int cnt = 0;
        int myr[NN - 1];
        int got[NN - 1];
        #pragma unroll
        for (int t = 0; t < NN - 1; ++t) { got[t] = -1; myr[t] = 0; }
        if (r > 0 && r < NPIX) {
            int v = ordA[r];
            int vi = v / HW, vj = v % HW;
            int pivot = (int)(pb[v] & 1023u);
            #pragma unroll
            for (int o = 0; o < NN; ++o) {
                int dx = ((DXPK >> (2 * o)) & 3) - 1;
                int dy = ((DYPK >> (2 * o)) & 3) - 1;
                int ui = vi + dx, uj = vj + dy;
                if ((unsigned)ui < (unsigned)HW && (unsigned)uj < (unsigned)HW) {
                    int u = ui * HW + uj;
                    unsigned e = pb[u];
                    if ((int)(e >> 10) < r) {
                        int b = (int)(e & 1023u);
                        bool dup = (b == pivot);
                        #pragma unroll
                        for (int t = 0; t < NN - 1; ++t) dup = dup || (got[t] == b);
                        if (!dup) {
                            #pragma unroll
                            for (int t = 0; t < NN - 1; ++t)
                                if (t == cnt) { got[t] = b; myr[t] = (v << 20) | (pivot << 10) | b; }
                            cnt++;
                        }
                    }
                }
            }
        }
        // block-wide exclusive prefix of cnt (16 wave partials)
        int p = cnt;
        for (int off = 1; off < 64; off <<= 1) {
            int t2 = __shfl_up(p, off, 64);
            if (lane >= off) p += t2;
        }
        if (lane == 63) wtot16[wv] = p;
        __syncthreads();
        int wadd = 0;
        for (int w2 = 0; w2 < wv; ++w2) wadd += wtot16[w2];
        int tot = 0;
        #pragma unroll
        for (int w2 = 0; w2 < 16; ++w2) tot += wtot16[w2];
        int excl = wadd + p - cnt;
        #pragma unroll
        for (int t = 0; t < NN - 1; ++t)
            if (t < cnt) recs[excl + t] = myr[t];
        nrec = tot;
        __syncthreads();
    }

    // ---- P5: ballot-driven serial UF (wave 0), block-wide flatten ----
    int k = 0;
    for (int base = 0; base < nrec; base += 64) {
        int nrem = 0;
        if (wv == 0) {
            int idx = base + lane;
            int rec = (idx < nrec) ? recs[idx] : 0;
            int pa = (rec >> 10) & 1023, pbn = rec & 1023;
            int ka = 0, kb = 0;
            if (idx < nrec) { ka = comp[pa]; kb = comp[pbn]; }
            for (;;) {
                unsigned long long d = __ballot(ka != kb);
                if (d == 0ull) break;
                int i = (int)__ffsll((long long)d) - 1;   // lowest lane = lowest rank
                int sA = __builtin_amdgcn_readlane(ka, i);
                int sB = __builtin_amdgcn_readlane(kb, i);
                int w = min(sA, sB), l = max(sA, sB);     // uniform scalars
                int sv = __builtin_amdgcn_readlane(rec, i) >> 20;
                if (lane == 0) {
                    pairsI[k] = (l & 1023) | (sv << 10);
                    mergeLDS[nrem] = make_int2(l, w);
                }
                k++;
                ka = (ka == l) ? w : ka;
                kb = (kb == l) ? w : kb;
                nrem++;
                if (nrem == 63) {              // overflow guard (rare): wave-0 flatten
                    for (int s = lane; s < NPIX; s += 64) {
                        int cv = comp[s], c0 = cv;
                        for (int e = 0; e < nrem; ++e) {
                            int2 me = mergeLDS[e];
                            cv = (cv == me.x) ? me.y : cv;
                        }
                        if (cv != c0) comp[s] = cv;
                    }
                    if (idx < nrec) { ka = comp[pa]; kb = comp[pbn]; }
                    nrem = 0;
                }
            }
            if (lane == 0) shInts[0] = nrem;
        }
        __syncthreads();
        int nr = shInts[0];
        if (nr > 0) {                          // flatten with all 1024 threads
            for (int s = tid; s < NPIX; s += 1024) {
                int cv = comp[s], c0 = cv;
                for (int e = 0; e < nr; ++e) {
                    int2 me = mergeLDS[e];
                    cv = (cv == me.x) ? me.y : cv;
                }
                if (cv != c0) comp[s] = cv;
            }
        }
        __syncthreads();
    }
    if (tid == 0) shInts[1] = k;
    __syncthreads();
    return shInts[1];
}

__global__ void __launch_bounds__(1024) uf_land_kernel(const float* __restrict__ F,
                                                       float* __restrict__ LAM1,
                                                       float* __restrict__ LAM2) {
    __shared__ int posA[NPIX], ordA[NPIX], bas[NPIX], comp[NPIX], pairsI[NPIX];
    __shared__ unsigned int pbArr[NPIX];  // packed (pos,bas) for P4
    __shared__ alignas(16) unsigned long long key64[NPIX];  // rank keys
    __shared__ float fv[NPIX];
    __shared__ int recs[MAXREC];
    __shared__ int2 mergeLDS[64];
    __shared__ int shInts[2];
    __shared__ int wtot16[16];
    int tid = threadIdx.x;
    int task = blockIdx.x;
    int feat = task >> 7;
    int dir = (task >> 6) & 1;
    int m = task & 63;
    const float* fr = F + feat * NIMG * NPIX + m * NPIX;

    // load values + precomputed packed u64 sort keys (values >= 0: bits
    // monotone; dir==1 uses ~bits so both dirs are the same ascending cmp)
    for (int j = tid; j < NPIX; j += 1024) {
        float f = fr[j];
        fv[j] = f;
        unsigned int b = __float_as_uint(f);
        if (dir) b = ~b;
        key64[j] = ((unsigned long long)b << 10) | (unsigned)j;
    }
    __syncthreads();

    // ---- fused rank: b128 reads of prepacked u64 keys, 1 cmp each ----
    if (tid < NPIX) {
        unsigned long long pki = key64[tid];
        int rank = 0;
        const ulonglong2* k2 = (const ulonglong2*)key64;
        for (int c = 0; c < NPIX / 2; ++c) {
            ulonglong2 kv = k2[c];
            rank += (int)(kv.x < pki) + (int)(kv.y < pki);
        }
        posA[tid] = rank;
        ordA[rank] = tid;
    }
    __syncthreads();
    for (int s = tid; s < NPIX; s += 1024) comp[s] = (posA[s] << 10) | s;
    // (comp init needs no barrier before P2: P2 reads only posA)

    int k;
    if (dir == 0) k = uf_basin_run<4>(posA, ordA, bas, pbArr, comp, recs, pairsI,
                                      mergeLDS, shInts, wtot16);
    else          k = uf_basin_run<8>(posA, ordA, bas, pbArr, comp, recs, pairsI,
                                      mergeLDS, shInts, wtot16);

    // ---- fused landscape: top-3 tents directly from pairsI (broadcast) ----
    if (tid < 32) {
        int t = tid;
        float start = (feat == 0) ? 0.f : 1.f;
        float end   = (feat == 0) ? 7.f : 8.f;
        float tv = start + (end - start) * ((float)t / 31.f);
        float v0 = 0.f, v1 = 0.f, v2 = 0.f;
        for (int p = 0; p < k; ++p) {
            int pi = pairsI[p];                   // same addr all lanes
            float fb = fv[pi & 1023], fd = fv[pi >> 10];
            float bb = dir ? fd : fb;
            float dd = dir ? fb : fd;
            float tent = fmaxf(fminf(tv - bb, dd - tv), 0.f);
            if (tent > v0)      { v2 = v1; v1 = v0; v0 = tent; }
            else if (tent > v1) { v2 = v1; v1 = tent; }
            else if (tent > v2) { v2 = tent; }
        }
        if (feat == 0) {
            float* lam = LAM1 + m * 128 + dir * 64;
            lam[0 * 32 + t] = v0;
            lam[1 * 32 + t] = v1;
        } else {
            float* lam = LAM2 + m * 192 + dir * 96;
            lam[0 * 32 + t] = v0;
            lam[1 * 32 + t] = v1;
            lam[2 * 32 + t] = v2;
        }
    }
}

// ---------------------------------------------------------------------------
// Kernel 4: MLP head. One block (64 threads) per image.
// ---------------------------------------------------------------------------
__global__ void mlp_kernel(const float* __restrict__ LAM1, const float* __restrict__ LAM2,
                           const float* __restrict__ w1, const float* __restrict__ b1,
                           const float* __restrict__ w2, const float* __restrict__ b2,
                           const float* __restrict__ wf, const float* __restrict__ bf,
                           float* __restrict__ out) {
    __shared__ float xc[64];
    int m = blockIdx.x;
    int n = threadIdx.x;
    if (n < 32) {
        float acc = b1[n];
        const float* l = LAM1 + m * 128;
        for (int c = 0; c < 128; ++c) acc += w1[n * 128 + c] * l[c];
        xc[n] = fmaxf(acc, 0.f);
    } else {
        int n2 = n - 32;
        float acc = b2[n2];
        const float* l = LAM2 + m * 192;
        for (int c = 0; c < 192; ++c) acc += w2[n2 * 192 + c] * l[c];
        xc[n] = fmaxf(acc, 0.f);
    }
    __syncthreads();
    if (n < 10) {
        float acc = bf[n];
        for (int c = 0; c < 64; ++c) acc += wf[n * 64 + c] * xc[c];
        out[m * 10 + n] = acc;
    }
}

extern "C" void kernel_launch(void* const* d_in, const int* in_sizes, int n_in,
                              void* d_out, int out_size, void* d_ws, size_t ws_size,
                              hipStream_t stream) {
    const float* x  = (const float*)d_in[0];
    const float* w1 = (const float*)d_in[1];
    const float* b1 = (const float*)d_in[2];
    const float* w2 = (const float*)d_in[3];
    const float* b2 = (const float*)d_in[4];
    const float* wf = (const float*)d_in[5];
    const float* bf = (const float*)d_in[6];
    float* out = (float*)d_out;

    char* ws = (char*)d_ws;
    size_t off = 0;
    float* XT   = (float*)(ws + off); off += (size_t)NPIX * NIMG * 4;
    float* SUMS = (float*)(ws + off); off += 256;
    float* F    = (float*)(ws + off); off += (size_t)2 * NIMG * NPIX * 4;
    float* LAM1 = (float*)(ws + off); off += (size_t)NIMG * 128 * 4;
    float* LAM2 = (float*)(ws + off); off += (size_t)NIMG * 192 * 4;

    xt_sums_kernel<<<NIMG, 256, 0, stream>>>(x, SUMS, XT);
    sortdtm_kernel<<<NPIX, 256, 0, stream>>>(XT, SUMS, F);
    uf_land_kernel<<<256, 1024, 0, stream>>>(F, LAM1, LAM2);
    mlp_kernel<<<NIMG, 64, 0, stream>>>(LAM1, LAM2, w1, b1, w2, b2, wf, bf, out);
}